// Round 13
// baseline (7747.546 us; speedup 1.0000x reference)
//
#include <hip/hip_runtime.h>
#include <math.h>

// Problem constants (fixed by the reference).
#define DIM   768
#define HID   1536
#define NCAT  2304            // HID + DIM (W1 | Wm concatenated on output dim)
#define BATCH 2048
#define NELEM (BATCH * DIM)   // 1572864
#define BANDS 32              // 2048 / 64-row GEMM0 bands
#define TILES_PER_BAND 24     // GEMM0 n-tiles per band (NCAT/96)
#define CNT_STRIDE 16         // uints: 64 B per band counter (own cache line)

typedef _Float16 f16x8 __attribute__((ext_vector_type(8)));
typedef _Float16 f16x4 __attribute__((ext_vector_type(4)));
typedef float f32x4 __attribute__((ext_vector_type(4)));

// ---------- numeric helpers ----------
__device__ __forceinline__ float fast_tanh(float x) {
  float e = __expf(2.0f * x);
  return 1.0f - 2.0f / (e + 1.0f);
}

// ---------- async global->LDS staging ----------
#define AS1 __attribute__((address_space(1)))
#define AS3 __attribute__((address_space(3)))
__device__ __forceinline__ void gload_lds16(const void* g, void* l) {
  __builtin_amdgcn_global_load_lds((const AS1 unsigned int*)g,
                                   (AS3 unsigned int*)l, 16, 0, 0);
}

// Stage a ROWSx64 fp16 tile (128 B rows) from row-major [.][K] global into
// LDS. Linear LDS dest (global_load_lds requirement); 16B slot index is
// XOR-swizzled via the GLOBAL source address; reads apply the same swizzle
// (rule #21). One wave-issue covers 8 rows (8 slots x 8 rows = 64 lanes).
template <int ROWS>
__device__ __forceinline__ void stage_tile(const _Float16* __restrict__ g,
                                           int K, char* lds, int w, int l) {
  constexpr int NCH = ROWS / 8;   // 1 KiB chunks
  const int sub  = l >> 3;        // row within 8-row chunk (== row & 7)
  const int slot = (l & 7) ^ sub; // inverse-swizzled source slot
#pragma unroll
  for (int i = 0; i < NCH / 4; ++i) {
    const int j = w + i * 4;      // chunk id, wave-uniform
    const int row = j * 8 + sub;
    gload_lds16(g + (size_t)row * K + slot * 8, lds + j * 1024);
  }
}

// Swizzled 16B fragment read. kk = k32 sub-block (0/1), lq = lane>>4.
__device__ __forceinline__ f16x8 ldfrag(const char* base, int row, int kk,
                                        int lq) {
  const int slot = (kk * 4 + lq) ^ (row & 7);
  return *reinterpret_cast<const f16x8*>(base + row * 128 + slot * 16);
}

// ---------- pipelined MFMA GEMM core (bit-identical to R9) ----------
// NBUF=2: depth-1 prefetch, two raw s_barriers per K-step.
// NBUF=3: depth-2 prefetch, one raw s_barrier per K-step.
// Counted s_waitcnt vmcnt(SISS) before the barrier; vmcnt never drains to 0
// mid-loop. __syncthreads() deliberately unused in the K-loop (hipcc pairs it
// with a vmcnt(0) drain — the m97 stall).
template <int BM, int BN, int KITERS, int NBUF, int WM, int WN>
__device__ __forceinline__ void gemm_core(
    const _Float16* __restrict__ Ag, const _Float16* __restrict__ Bg,
    char* smem, int w, int l, int lr, int lq, int wr, int wc,
    f32x4 (&acc)[WM][WN]) {
  constexpr int K = KITERS * 64;
  constexpr int BUF = (BM + BN) * 128;
  constexpr int SISS = BM / 32 + BN / 32;

#pragma unroll
  for (int m = 0; m < WM; ++m)
#pragma unroll
    for (int n = 0; n < WN; ++n) acc[m][n] = f32x4{0.f, 0.f, 0.f, 0.f};

  auto STAGE = [&](int t) {
    char* base = smem + (t % NBUF) * BUF;
    stage_tile<BM>(Ag + t * 64, K, base, w, l);
    stage_tile<BN>(Bg + t * 64, K, base + BM * 128, w, l);
  };

  STAGE(0);
  if (NBUF == 3 && KITERS > 1) STAGE(1);

  for (int kt = 0; kt < KITERS; ++kt) {
    if (NBUF == 2 && kt + 1 < KITERS) STAGE(kt + 1);
    if (kt + 1 < KITERS)
      asm volatile("s_waitcnt vmcnt(%0)" ::"n"(SISS) : "memory");
    else
      asm volatile("s_waitcnt vmcnt(0)" ::: "memory");
    __builtin_amdgcn_s_barrier();
    __builtin_amdgcn_sched_barrier(0);
    if (NBUF == 3 && kt + 2 < KITERS) STAGE(kt + 2);

    const char* As = smem + (kt % NBUF) * BUF;
    const char* Bs = As + BM * 128;
#pragma unroll
    for (int kk = 0; kk < 2; ++kk) {
      f16x8 afr[WM], bfr[WN];
#pragma unroll
      for (int n = 0; n < WN; ++n) bfr[n] = ldfrag(Bs, wc + n * 16 + lr, kk, lq);
#pragma unroll
      for (int m = 0; m < WM; ++m) afr[m] = ldfrag(As, wr + m * 16 + lr, kk, lq);
      __builtin_amdgcn_s_setprio(1);
#pragma unroll
      for (int m = 0; m < WM; ++m)
#pragma unroll
        for (int n = 0; n < WN; ++n)
          acc[m][n] = __builtin_amdgcn_mfma_f32_16x16x32_f16(afr[m], bfr[n],
                                                             acc[m][n], 0, 0, 0);
      __builtin_amdgcn_s_setprio(0);
    }
    if (NBUF == 2) __builtin_amdgcn_s_barrier();
  }
}

// ---------- one RK stage = one kernel, band-flag producer/consumer ----------
// Grid 768 x 256, 48 KB LDS, LB(256,3): all 768 blocks co-resident (proven by
// R10's 37.4% occupancy) -> spinning is deadlock-free.
// Phase A (all 768 blocks): one 64x96 GEMM0 tile, then RELEASE fetch_add on
//   this band's padded counter (24 producers/band, 32 independent 64B lines).
// Phase B (blocks 0..511): RELAXED poll until cnt[band] == 24 (coherent load,
//   NO per-poll invalidate — R11's per-poll ACQUIRE caused an L2 invalidation
//   storm: 134 us/stage at 4% HBM efficiency), then ONE ACQUIRE load to
//   invalidate stale lines, then GEMM1 + fused RK epilogue.
// WAR safety: band b's 24 producers are exactly the readers of band b's ts
// rows, so cnt[b]==24 also licenses overwriting ts/accb in that band.
__global__ __launch_bounds__(256, 3) void stage_k(
    _Float16* __restrict__ ys, _Float16* __restrict__ ts,
    _Float16* __restrict__ Hh, const _Float16* __restrict__ WcatT,
    const _Float16* __restrict__ W2T, const float* __restrict__ bias_cat,
    _Float16* __restrict__ kmem, _Float16* __restrict__ accb,
    float* __restrict__ y, float* __restrict__ out_row,
    const float* __restrict__ b2, const float* __restrict__ tg,
    unsigned* __restrict__ cnt, int step, int sub) {
  __shared__ __align__(16) char smem[49152];  // GEMM0 2x20K=40K; GEMM1 3x16K=48K

  const int tid = threadIdx.x;
  const int w = tid >> 6, l = tid & 63;
  const int lr = l & 15, lq = l >> 4;
  const int flat = blockIdx.x;
  const int xcd = flat & 7, slot = flat >> 3;

  // ---------- Phase A: GEMM0 tile (64x96, wave 32x48 m2n3, NBUF=2) ----------
  {
    const int mt = (xcd & 1) * 16 + (slot & 15);   // [0,32)
    const int nt = (xcd >> 1) * 6 + (slot >> 4);   // [0,24)
    const int m0 = mt * 64, n0 = nt * 96;
    const int wr = (w >> 1) * 32, wc = (w & 1) * 48;
    const _Float16* A = (sub == 0) ? ys : ts;
    f32x4 acc[2][3];
    gemm_core<64, 96, 12, 2, 2, 3>(A + (size_t)m0 * DIM,
                                   WcatT + (size_t)n0 * DIM, smem, w, l, lr,
                                   lq, wr, wc, acc);
    // Epilogue: t = tanh(acc + bias); col<HID -> Hh fp16, else kmem fp16.
    // C/D layout (m89-verified): col = lane&15, row = (lane>>4)*4 + j.
#pragma unroll
    for (int m = 0; m < 2; ++m)
#pragma unroll
      for (int n = 0; n < 3; ++n) {
        const int gcol = n0 + wc + n * 16 + lr;
        const float bv = bias_cat[gcol];
#pragma unroll
        for (int j = 0; j < 4; ++j) {
          const int grow = m0 + wr + m * 16 + lq * 4 + j;
          const float t = fast_tanh(acc[m][n][j] + bv);
          if (gcol < HID)
            Hh[(size_t)grow * HID + gcol] = (_Float16)t;
          else
            kmem[(size_t)grow * DIM + (gcol - HID)] = (_Float16)t;
        }
      }
    __syncthreads();  // hipcc pairs with vmcnt(0): all epilogue stores done
    if (tid == 0)
      __hip_atomic_fetch_add(&cnt[mt * CNT_STRIDE], 1u, __ATOMIC_RELEASE,
                             __HIP_MEMORY_SCOPE_AGENT);
  }

  // ---------- Phase B: GEMM1 tile (32x96, wave 16x48 m1n3, NBUF=3) ----------
  if (flat < 512) {
    const int m0 = (xcd * 8 + (slot & 7)) * 32;  // [0,2048)
    const int n0 = (slot >> 3) * 96;             // [0,768)
    const int band = m0 >> 6;                    // covering 64-row band
    if (tid == 0) {
      // RELAXED coherent polls (no invalidate); R10 proved these observe
      // remote device-scope RMWs.
      while (__hip_atomic_load(&cnt[band * CNT_STRIDE], __ATOMIC_RELAXED,
                               __HIP_MEMORY_SCOPE_AGENT) < TILES_PER_BAND)
        __builtin_amdgcn_s_sleep(8);
      // Exactly ONE acquire (single invalidate) before reading Hh/kmem.
      (void)__hip_atomic_load(&cnt[band * CNT_STRIDE], __ATOMIC_ACQUIRE,
                              __HIP_MEMORY_SCOPE_AGENT);
    }
    __syncthreads();

    const int wr = (w >> 1) * 16, wc = (w & 1) * 48;
    f32x4 acc[1][3];
    gemm_core<32, 96, 24, 3, 1, 3>(Hh + (size_t)m0 * HID,
                                   W2T + (size_t)n0 * HID, smem, w, l, lr, lq,
                                   wr, wc, acc);
    const float h = tg[step + 1] - tg[step];
    const float hmul = (sub == 2) ? 1.0f : 0.5f;
#pragma unroll
    for (int n = 0; n < 3; ++n) {
      const int gcol = n0 + wc + n * 16 + lr;
      const float bv = b2[gcol];
#pragma unroll
      for (int j = 0; j < 4; ++j) {
        const int grow = m0 + wr + lq * 4 + j;
        const size_t idx = (size_t)grow * DIM + gcol;
        const float kv = acc[0][n][j] + (float)kmem[idx] + bv;
        if (sub < 3) {
          const float av = (sub == 0) ? kv : ((float)accb[idx] + 2.0f * kv);
          accb[idx] = (_Float16)av;
          const float tv = y[idx] + (hmul * h) * kv;
          ts[idx] = (_Float16)tv;
        } else {
          const float v =
              y[idx] + (h * (1.0f / 6.0f)) * ((float)accb[idx] + kv);
          y[idx] = v;
          out_row[idx] = v;
          ys[idx] = (_Float16)v;
        }
      }
    }
  }
}

// ---------- init + weight prep ----------
__global__ __launch_bounds__(256) void init_k(
    const float* __restrict__ x, float* __restrict__ y,
    float* __restrict__ out0, _Float16* __restrict__ ys) {
  const int i4 = blockIdx.x * 256 + threadIdx.x;
  const int base = i4 * 4;
  f32x4 v = *(const f32x4*)(x + base);
  *(f32x4*)(y + base) = v;
  *(f32x4*)(out0 + base) = v;
  f16x4 hv;
#pragma unroll
  for (int j = 0; j < 4; ++j) hv[j] = (_Float16)v[j];
  *(f16x4*)(ys + base) = hv;
}

__global__ __launch_bounds__(256) void prep_wcat_k(
    const float* __restrict__ W1, const float* __restrict__ Wm,
    _Float16* __restrict__ out) {  // [NCAT][DIM] = concat(W1^T, Wm^T)
  const int idx = blockIdx.x * 256 + threadIdx.x;
  const int nrow = idx / DIM, k = idx % DIM;
  const float v = (nrow < HID) ? W1[(size_t)k * HID + nrow]
                               : Wm[(size_t)k * DIM + (nrow - HID)];
  out[idx] = (_Float16)v;
}
__global__ __launch_bounds__(256) void prep_w2t_k(
    const float* __restrict__ W2, _Float16* __restrict__ out) {  // [DIM][HID]
  const int idx = blockIdx.x * 256 + threadIdx.x;
  const int nrow = idx / HID, k = idx % HID;
  out[idx] = (_Float16)W2[(size_t)k * DIM + nrow];
}
__global__ __launch_bounds__(256) void prep_bias_k(
    const float* __restrict__ b1, const float* __restrict__ bmv,
    float* __restrict__ out) {  // [NCAT]
  const int i = blockIdx.x * 256 + threadIdx.x;
  if (i < NCAT) out[i] = (i < HID) ? b1[i] : bmv[i - HID];
}

extern "C" void kernel_launch(void* const* d_in, const int* in_sizes, int n_in,
                              void* d_out, int out_size, void* d_ws,
                              size_t ws_size, hipStream_t stream) {
  const float* x  = (const float*)d_in[0];
  const float* tg = (const float*)d_in[1];
  const float* W1 = (const float*)d_in[2];
  const float* b1 = (const float*)d_in[3];
  const float* W2 = (const float*)d_in[4];
  const float* b2 = (const float*)d_in[5];
  const float* Wm = (const float*)d_in[6];
  const float* bm = (const float*)d_in[7];
  float* out = (float*)d_out;
  const int T = in_sizes[1];  // 32
  const int nstage = (T - 1) * 4;

  // ---- workspace partition; cnt region first (124 * 32 * 64B = 254 KB) ----
  unsigned* cnt   = (unsigned*)d_ws;               // nstage*BANDS*CNT_STRIDE
  float* y        = (float*)((char*)d_ws + 262144);
  float* bias_cat = y + NELEM;                     // NCAT
  _Float16* kmem  = (_Float16*)(bias_cat + NCAT);  // NELEM fp16
  _Float16* accb  = kmem + NELEM;                  // NELEM fp16
  _Float16* ys    = accb + NELEM;                  // NELEM (state y, fp16)
  _Float16* ts    = ys + NELEM;                    // NELEM (stage state)
  _Float16* Hh    = ts + NELEM;                    // BATCH*HID
  _Float16* WcatT = Hh + (size_t)BATCH * HID;      // NCAT*DIM
  _Float16* W2T   = WcatT + (size_t)NCAT * DIM;    // DIM*HID

  // ---- per-launch prep ----
  hipMemsetAsync(cnt, 0, (size_t)nstage * BANDS * CNT_STRIDE * 4, stream);
  prep_wcat_k<<<(NCAT * DIM) / 256, 256, 0, stream>>>(W1, Wm, WcatT);
  prep_w2t_k<<<(DIM * HID) / 256, 256, 0, stream>>>(W2, W2T);
  prep_bias_k<<<(NCAT + 255) / 256, 256, 0, stream>>>(b1, bm, bias_cat);
  init_k<<<NELEM / 1024, 256, 0, stream>>>(x, y, out, ys);

  // ---- one kernel per RK stage ----
  for (int s = 0; s < nstage; ++s) {
    const int step = s >> 2, sub = s & 3;
    stage_k<<<768, 256, 0, stream>>>(
        ys, ts, Hh, WcatT, W2T, bias_cat, kmem, accb, y,
        out + (size_t)(step + 1) * NELEM, b2, tg,
        cnt + (size_t)s * BANDS * CNT_STRIDE, step, sub);
  }
}

// Round 14
// 3932.509 us; speedup vs baseline: 1.9701x; 1.9701x over previous
//
#include <hip/hip_runtime.h>
#include <math.h>

// Problem constants (fixed by the reference).
#define DIM   768
#define HID   1536
#define NCAT  2304            // HID + DIM (W1 | Wm concatenated on output dim)
#define BATCH 2048
#define NELEM (BATCH * DIM)   // 1572864

typedef _Float16 f16x8 __attribute__((ext_vector_type(8)));
typedef _Float16 f16x4 __attribute__((ext_vector_type(4)));
typedef float f32x4 __attribute__((ext_vector_type(4)));

// ---------- numeric helpers ----------
__device__ __forceinline__ float fast_tanh(float x) {
  float e = __expf(2.0f * x);
  return 1.0f - 2.0f / (e + 1.0f);
}

// ---------- async global->LDS staging ----------
#define AS1 __attribute__((address_space(1)))
#define AS3 __attribute__((address_space(3)))
__device__ __forceinline__ void gload_lds16(const void* g, void* l) {
  __builtin_amdgcn_global_load_lds((const AS1 unsigned int*)g,
                                   (AS3 unsigned int*)l, 16, 0, 0);
}

// Stage a ROWSx64 fp16 tile (128 B rows) from row-major [.][K] global into
// LDS. Linear LDS dest (global_load_lds requirement); 16B slot index is
// XOR-swizzled via the GLOBAL source address; reads apply the same swizzle
// (rule #21). One wave-issue covers 8 rows (8 slots x 8 rows = 64 lanes).
template <int ROWS>
__device__ __forceinline__ void stage_tile(const _Float16* __restrict__ g,
                                           int K, char* lds, int w, int l) {
  constexpr int NCH = ROWS / 8;   // 1 KiB chunks
  const int sub  = l >> 3;        // row within 8-row chunk (== row & 7)
  const int slot = (l & 7) ^ sub; // inverse-swizzled source slot
#pragma unroll
  for (int i = 0; i < NCH / 4; ++i) {
    const int j = w + i * 4;      // chunk id, wave-uniform
    const int row = j * 8 + sub;
    gload_lds16(g + (size_t)row * K + slot * 8, lds + j * 1024);
  }
}

// Swizzled 16B fragment read. kk = k32 sub-block (0/1), lq = lane>>4.
__device__ __forceinline__ f16x8 ldfrag(const char* base, int row, int kk,
                                        int lq) {
  const int slot = (kk * 4 + lq) ^ (row & 7);
  return *reinterpret_cast<const f16x8*>(base + row * 128 + slot * 16);
}

// ---------- pipelined MFMA GEMM (fp16 in, fp32 accum) — R9 proven config ----
// MODE 0: state GEMM, tile 64x96 (wave 32x48 m2n3), DOUBLE-buffered
//   (40 KB -> grid 768 = 3/CU all-resident, 12 waves/CU), depth-1 prefetch,
//   two raw s_barriers per K-step. Epilogue t = tanh(acc+bias):
//   col<HID -> Hh fp16, else kmem fp16.
// MODE 1/2: dyn GEMM (A = H, K = HID), tile 32x96 (wave 16x48 m1n3),
//   TRIPLE-buffered depth-2, one barrier per K-step, grid 512 = 2/CU
//   (8 waves/CU). Fused RK epilogues:
//   MODE 1 (STAGE): kv = acc + kmem + b2; accb = init? kv : accb+2kv;
//                   tv = y + hmul*h*kv -> ts fp16.
//   MODE 2 (FINAL): kv = acc + kmem + b2; y += h/6*(accb+kv); out_row = y;
//                   ts = fp16(y).
// Counted s_waitcnt vmcnt(SISS) before each raw barrier; vmcnt never drains
// to 0 mid-loop (in-flight prefetch crosses the barrier). __syncthreads()
// deliberately unused in the K-loop (hipcc pairs it with a vmcnt(0) drain —
// the m97 stall). Geometry notes fixed by measurement:
//   - >=8-12 waves/CU beats better per-wave LDS ratios (R8/R12 regressions).
//   - fine-grained cross-block sync is 2-9x worse than kernel boundaries on
//     gfx950 (R10/R11/R13): agent-scope release/acquire => L2 wb/inv storms.
template <int MODE, int BM, int BN, int KITERS>
__global__ __launch_bounds__(256, (MODE == 0) ? 3 : 2) void gemm_k(
    const _Float16* __restrict__ A, const _Float16* __restrict__ Bt,
    const float* __restrict__ bias, _Float16* __restrict__ Hout,
    _Float16* __restrict__ kmem, const float* __restrict__ b2,
    float* __restrict__ y, _Float16* __restrict__ accb,
    _Float16* __restrict__ ts, float* __restrict__ out_row,
    const float* __restrict__ tg, int step, float hmul, int initf) {
  constexpr int K = KITERS * 64;
  constexpr int WM = BM / 32;      // m-frags per wave (2x2 wave grid)
  constexpr int WN = BN / 32;      // n-frags per wave
  constexpr int BUF = (BM + BN) * 128;       // one K64 double-tile
  constexpr int NBUF = (MODE == 0) ? 2 : 3;  // buffers in rotation
  constexpr int SISS = BM / 32 + BN / 32;    // stage issues per wave per tile
  __shared__ __align__(16) char smem[NBUF * BUF];

  const int tid = threadIdx.x;
  const int w = tid >> 6, l = tid & 63;
  const int lr = l & 15, lq = l >> 4;

  // XCD-locality decode (bijective; flat%8 -> XCD round-robin heuristic).
  const int flat = blockIdx.x;
  const int xcd = flat & 7, slot = flat >> 3;
  int mt, nt;
  if (MODE == 0) {
    mt = (xcd & 1) * 16 + (slot & 15);   // [0,32)
    nt = (xcd >> 1) * 6 + (slot >> 4);   // [0,24)
  } else {
    mt = xcd * 8 + (slot & 7);           // [0,64)
    nt = slot >> 3;                      // [0,8)
  }
  const int m0 = mt * BM;
  const int n0 = nt * BN;
  const int wr = (w >> 1) * (WM * 16);
  const int wc = (w & 1) * (WN * 16);

  const _Float16* Ag = A + (size_t)m0 * K;
  const _Float16* Bg = Bt + (size_t)n0 * K;

  f32x4 acc[WM][WN];
#pragma unroll
  for (int m = 0; m < WM; ++m)
#pragma unroll
    for (int n = 0; n < WN; ++n) acc[m][n] = f32x4{0.f, 0.f, 0.f, 0.f};

  auto STAGE = [&](int t) {
    char* base = smem + (t % NBUF) * BUF;
    stage_tile<BM>(Ag + t * 64, K, base, w, l);
    stage_tile<BN>(Bg + t * 64, K, base + BM * 128, w, l);
  };

  STAGE(0);
  if (NBUF == 3 && KITERS > 1) STAGE(1);

  for (int kt = 0; kt < KITERS; ++kt) {
    if (NBUF == 2 && kt + 1 < KITERS) STAGE(kt + 1);
    // Wait for tile kt's own-wave loads only; newer tiles stay in flight
    // ACROSS the raw barrier (no compiler vmcnt(0) drain).
    if (kt + 1 < KITERS)
      asm volatile("s_waitcnt vmcnt(%0)" ::"n"(SISS) : "memory");
    else
      asm volatile("s_waitcnt vmcnt(0)" ::: "memory");
    __builtin_amdgcn_s_barrier();
    __builtin_amdgcn_sched_barrier(0);
    if (NBUF == 3 && kt + 2 < KITERS) STAGE(kt + 2);

    const char* As = smem + (kt % NBUF) * BUF;
    const char* Bs = As + BM * 128;
#pragma unroll
    for (int kk = 0; kk < 2; ++kk) {
      f16x8 afr[WM], bfr[WN];
#pragma unroll
      for (int n = 0; n < WN; ++n) bfr[n] = ldfrag(Bs, wc + n * 16 + lr, kk, lq);
#pragma unroll
      for (int m = 0; m < WM; ++m) afr[m] = ldfrag(As, wr + m * 16 + lr, kk, lq);
      __builtin_amdgcn_s_setprio(1);
#pragma unroll
      for (int m = 0; m < WM; ++m)
#pragma unroll
        for (int n = 0; n < WN; ++n)
          acc[m][n] = __builtin_amdgcn_mfma_f32_16x16x32_f16(afr[m], bfr[n],
                                                             acc[m][n], 0, 0, 0);
      __builtin_amdgcn_s_setprio(0);
    }
    if (NBUF == 2) __builtin_amdgcn_s_barrier();  // fence buf rewrite next iter
  }

  // Epilogue. C/D layout (m89-verified): col = lane&15, row = (lane>>4)*4 + j.
  if (MODE == 0) {
#pragma unroll
    for (int m = 0; m < WM; ++m)
#pragma unroll
      for (int n = 0; n < WN; ++n) {
        const int gcol = n0 + wc + n * 16 + lr;
        const float bv = bias[gcol];
#pragma unroll
        for (int j = 0; j < 4; ++j) {
          const int grow = m0 + wr + m * 16 + lq * 4 + j;
          const float t = fast_tanh(acc[m][n][j] + bv);
          if (gcol < HID)
            Hout[(size_t)grow * HID + gcol] = (_Float16)t;
          else
            kmem[(size_t)grow * DIM + (gcol - HID)] = (_Float16)t;
        }
      }
  } else {
    const float h = tg[step + 1] - tg[step];
#pragma unroll
    for (int m = 0; m < WM; ++m)
#pragma unroll
      for (int n = 0; n < WN; ++n) {
        const int gcol = n0 + wc + n * 16 + lr;
        const float bv = b2[gcol];
#pragma unroll
        for (int j = 0; j < 4; ++j) {
          const int grow = m0 + wr + m * 16 + lq * 4 + j;
          const size_t idx = (size_t)grow * DIM + gcol;
          const float kv = acc[m][n][j] + (float)kmem[idx] + bv;
          if (MODE == 1) {
            const float av = initf ? kv : ((float)accb[idx] + 2.0f * kv);
            accb[idx] = (_Float16)av;
            const float tv = y[idx] + (hmul * h) * kv;
            ts[idx] = (_Float16)tv;
          } else {
            const float v =
                y[idx] + (h * (1.0f / 6.0f)) * ((float)accb[idx] + kv);
            y[idx] = v;
            out_row[idx] = v;
            ts[idx] = (_Float16)v;
          }
        }
      }
  }
}

// ---------- merged one-time prep: weights + bias + state init ----------
// Grid covers max(NCAT*DIM, DIM*HID, NELEM/4) lanes of work; each sub-job
// guarded by range. One launch instead of four (boundaries cost ~3.6 us each).
__global__ __launch_bounds__(256) void prep_k(
    const float* __restrict__ x, const float* __restrict__ W1,
    const float* __restrict__ b1, const float* __restrict__ W2,
    const float* __restrict__ Wm, const float* __restrict__ bmv,
    float* __restrict__ y, float* __restrict__ out0,
    _Float16* __restrict__ ys, _Float16* __restrict__ WcatT,
    _Float16* __restrict__ W2T, float* __restrict__ bias_cat) {
  const int idx = blockIdx.x * 256 + threadIdx.x;

  // Job 1: WcatT [NCAT][DIM] = concat(W1^T, Wm^T)   (NCAT*DIM threads)
  {
    const int nrow = idx / DIM, k = idx % DIM;
    const float v = (nrow < HID) ? W1[(size_t)k * HID + nrow]
                                 : Wm[(size_t)k * DIM + (nrow - HID)];
    WcatT[idx] = (_Float16)v;
  }
  // Job 2: W2T [DIM][HID] = W2^T   (DIM*HID threads)
  if (idx < DIM * HID) {
    const int nrow = idx / HID, k = idx % HID;
    W2T[idx] = (_Float16)W2[(size_t)k * DIM + nrow];
  }
  // Job 3: bias_cat [NCAT]
  if (idx < NCAT) bias_cat[idx] = (idx < HID) ? b1[idx] : bmv[idx - HID];
  // Job 4: state init (NELEM/4 threads, float4 lanes)
  if (idx < NELEM / 4) {
    const int base = idx * 4;
    f32x4 v = *(const f32x4*)(x + base);
    *(f32x4*)(y + base) = v;
    *(f32x4*)(out0 + base) = v;
    f16x4 hv;
#pragma unroll
    for (int j = 0; j < 4; ++j) hv[j] = (_Float16)v[j];
    *(f16x4*)(ys + base) = hv;
  }
}

extern "C" void kernel_launch(void* const* d_in, const int* in_sizes, int n_in,
                              void* d_out, int out_size, void* d_ws,
                              size_t ws_size, hipStream_t stream) {
  const float* x  = (const float*)d_in[0];
  const float* tg = (const float*)d_in[1];
  const float* W1 = (const float*)d_in[2];
  const float* b1 = (const float*)d_in[3];
  const float* W2 = (const float*)d_in[4];
  const float* b2 = (const float*)d_in[5];
  const float* Wm = (const float*)d_in[6];
  const float* bm = (const float*)d_in[7];
  float* out = (float*)d_out;
  const int T = in_sizes[1];  // 32

  // ---- workspace partition (~30 MB) ----
  float* y        = (float*)d_ws;               // NELEM f32
  float* bias_cat = y + NELEM;                  // NCAT
  _Float16* kmem  = (_Float16*)(bias_cat + NCAT);  // NELEM fp16
  _Float16* accb  = kmem + NELEM;                  // NELEM fp16
  _Float16* ys    = accb + NELEM;                  // NELEM (state y, fp16)
  _Float16* ts    = ys + NELEM;                    // NELEM (stage state)
  _Float16* Hh    = ts + NELEM;                    // BATCH*HID
  _Float16* WcatT = Hh + (size_t)BATCH * HID;      // NCAT*DIM
  _Float16* W2T   = WcatT + (size_t)NCAT * DIM;    // DIM*HID

  // ---- one-time prep (single launch: weights, bias, state init) ----
  prep_k<<<(NCAT * DIM) / 256, 256, 0, stream>>>(x, W1, b1, W2, Wm, bm, y, out,
                                                 ys, WcatT, W2T, bias_cat);

  auto gemm0 = [&](const _Float16* a) {
    gemm_k<0, 64, 96, 12><<<768, 256, 0, stream>>>(
        a, WcatT, bias_cat, Hh, kmem, nullptr, nullptr, nullptr, nullptr,
        nullptr, nullptr, 0, 0.f, 0);
  };
  auto gemm1_stage = [&](int step, float hmul, int initf) {
    gemm_k<1, 32, 96, 24><<<512, 256, 0, stream>>>(
        Hh, W2T, nullptr, nullptr, kmem, b2, y, accb, ts, nullptr, tg, step,
        hmul, initf);
  };
  auto gemm1_final = [&](int step, float* orow) {
    gemm_k<2, 32, 96, 24><<<512, 256, 0, stream>>>(
        Hh, W2T, nullptr, nullptr, kmem, b2, y, accb, ys, orow, tg, step, 0.f,
        0);
  };

  for (int i = 0; i < T - 1; ++i) {
    gemm0(ys);  gemm1_stage(i, 0.5f, 1);   // k1
    gemm0(ts);  gemm1_stage(i, 0.5f, 0);   // k2
    gemm0(ts);  gemm1_stage(i, 1.0f, 0);   // k3
    gemm0(ts);  gemm1_final(i, out + (size_t)(i + 1) * NELEM);  // k4
  }
}

// Round 15
// 3869.614 us; speedup vs baseline: 2.0021x; 1.0163x over previous
//
#include <hip/hip_runtime.h>
#include <math.h>

// Problem constants (fixed by the reference).
#define DIM   768
#define HID   1536
#define NCAT  2304            // HID + DIM (W1 | Wm concatenated on output dim)
#define BATCH 2048
#define NELEM (BATCH * DIM)   // 1572864

typedef _Float16 f16x8 __attribute__((ext_vector_type(8)));
typedef _Float16 f16x4 __attribute__((ext_vector_type(4)));
typedef float f32x4 __attribute__((ext_vector_type(4)));

// ---------- numeric helpers ----------
__device__ __forceinline__ float fast_tanh(float x) {
  // tanh(x) = 1 - 2/(exp(2x)+1). v_rcp_f32 (~1 ulp) instead of the full
  // div_scale/fmas/fixup sequence: rel err ~6e-8, invisible at fp16 storage.
  // x>44 -> e=inf -> rcp=0 -> 1.0 (correct saturation).
  float e = __expf(2.0f * x);
  return 1.0f - 2.0f * __builtin_amdgcn_rcpf(e + 1.0f);
}

// ---------- async global->LDS staging ----------
#define AS1 __attribute__((address_space(1)))
#define AS3 __attribute__((address_space(3)))
__device__ __forceinline__ void gload_lds16(const void* g, void* l) {
  __builtin_amdgcn_global_load_lds((const AS1 unsigned int*)g,
                                   (AS3 unsigned int*)l, 16, 0, 0);
}

// Stage a ROWSx64 fp16 tile (128 B rows) from row-major [.][K] global into
// LDS. Linear LDS dest (global_load_lds requirement); 16B slot index is
// XOR-swizzled via the GLOBAL source address; reads apply the same swizzle
// (rule #21). One wave-issue covers 8 rows (8 slots x 8 rows = 64 lanes).
template <int ROWS>
__device__ __forceinline__ void stage_tile(const _Float16* __restrict__ g,
                                           int K, char* lds, int w, int l) {
  constexpr int NCH = ROWS / 8;   // 1 KiB chunks
  const int sub  = l >> 3;        // row within 8-row chunk (== row & 7)
  const int slot = (l & 7) ^ sub; // inverse-swizzled source slot
#pragma unroll
  for (int i = 0; i < NCH / 4; ++i) {
    const int j = w + i * 4;      // chunk id, wave-uniform
    const int row = j * 8 + sub;
    gload_lds16(g + (size_t)row * K + slot * 8, lds + j * 1024);
  }
}

// Swizzled 16B fragment read. kk = k32 sub-block (0/1), lq = lane>>4.
__device__ __forceinline__ f16x8 ldfrag(const char* base, int row, int kk,
                                        int lq) {
  const int slot = (kk * 4 + lq) ^ (row & 7);
  return *reinterpret_cast<const f16x8*>(base + row * 128 + slot * 16);
}

// ---------- pipelined MFMA GEMM (fp16 in, fp32 accum) — R9 proven config ----
// MODE 0: state GEMM, tile 64x96 (wave 32x48 m2n3), DOUBLE-buffered
//   (40 KB -> grid 768 = 3/CU all-resident, 12 waves/CU), depth-1 prefetch,
//   two raw s_barriers per K-step. Epilogue t = tanh(acc+bias):
//   col<HID -> Hh fp16, else kmem fp16.
// MODE 1/2: dyn GEMM (A = H, K = HID), tile 32x96 (wave 16x48 m1n3),
//   TRIPLE-buffered depth-2, one barrier per K-step, grid 512 = 2/CU
//   (8 waves/CU). Fused RK epilogues:
//   MODE 1 (STAGE): kv = acc + kmem + b2; accb = init? kv : accb+2kv;
//                   tv = y + hmul*h*kv -> ts fp16.
//   MODE 2 (FINAL): kv = acc + kmem + b2; y += h/6*(accb+kv); out_row = y;
//                   ts = fp16(y).
// Counted s_waitcnt vmcnt(SISS) before each raw barrier; vmcnt never drains
// to 0 mid-loop (in-flight prefetch crosses the barrier). __syncthreads()
// deliberately unused in the K-loop (hipcc pairs it with a vmcnt(0) drain —
// the m97 stall). Geometry notes fixed by measurement:
//   - >=8-12 waves/CU beats better per-wave LDS ratios (R8/R12 regressions).
//   - fine-grained cross-block sync is 2-9x worse than kernel boundaries on
//     gfx950 (R10/R11/R13): agent-scope release/acquire => L2 wb/inv storms.
template <int MODE, int BM, int BN, int KITERS>
__global__ __launch_bounds__(256, (MODE == 0) ? 3 : 2) void gemm_k(
    const _Float16* __restrict__ A, const _Float16* __restrict__ Bt,
    const float* __restrict__ bias, _Float16* __restrict__ Hout,
    _Float16* __restrict__ kmem, const float* __restrict__ b2,
    float* __restrict__ y, _Float16* __restrict__ accb,
    _Float16* __restrict__ ts, float* __restrict__ out_row,
    const float* __restrict__ tg, int step, float hmul, int initf) {
  constexpr int K = KITERS * 64;
  constexpr int WM = BM / 32;      // m-frags per wave (2x2 wave grid)
  constexpr int WN = BN / 32;      // n-frags per wave
  constexpr int BUF = (BM + BN) * 128;       // one K64 double-tile
  constexpr int NBUF = (MODE == 0) ? 2 : 3;  // buffers in rotation
  constexpr int SISS = BM / 32 + BN / 32;    // stage issues per wave per tile
  __shared__ __align__(16) char smem[NBUF * BUF];

  const int tid = threadIdx.x;
  const int w = tid >> 6, l = tid & 63;
  const int lr = l & 15, lq = l >> 4;

  // XCD-locality decode (bijective; flat%8 -> XCD round-robin heuristic).
  const int flat = blockIdx.x;
  const int xcd = flat & 7, slot = flat >> 3;
  int mt, nt;
  if (MODE == 0) {
    mt = (xcd & 1) * 16 + (slot & 15);   // [0,32)
    nt = (xcd >> 1) * 6 + (slot >> 4);   // [0,24)
  } else {
    mt = xcd * 8 + (slot & 7);           // [0,64)
    nt = slot >> 3;                      // [0,8)
  }
  const int m0 = mt * BM;
  const int n0 = nt * BN;
  const int wr = (w >> 1) * (WM * 16);
  const int wc = (w & 1) * (WN * 16);

  const _Float16* Ag = A + (size_t)m0 * K;
  const _Float16* Bg = Bt + (size_t)n0 * K;

  f32x4 acc[WM][WN];
#pragma unroll
  for (int m = 0; m < WM; ++m)
#pragma unroll
    for (int n = 0; n < WN; ++n) acc[m][n] = f32x4{0.f, 0.f, 0.f, 0.f};

  auto STAGE = [&](int t) {
    char* base = smem + (t % NBUF) * BUF;
    stage_tile<BM>(Ag + t * 64, K, base, w, l);
    stage_tile<BN>(Bg + t * 64, K, base + BM * 128, w, l);
  };

  STAGE(0);
  if (NBUF == 3 && KITERS > 1) STAGE(1);

  for (int kt = 0; kt < KITERS; ++kt) {
    if (NBUF == 2 && kt + 1 < KITERS) STAGE(kt + 1);
    // Wait for tile kt's own-wave loads only; newer tiles stay in flight
    // ACROSS the raw barrier (no compiler vmcnt(0) drain).
    if (kt + 1 < KITERS)
      asm volatile("s_waitcnt vmcnt(%0)" ::"n"(SISS) : "memory");
    else
      asm volatile("s_waitcnt vmcnt(0)" ::: "memory");
    __builtin_amdgcn_s_barrier();
    __builtin_amdgcn_sched_barrier(0);
    if (NBUF == 3 && kt + 2 < KITERS) STAGE(kt + 2);

    const char* As = smem + (kt % NBUF) * BUF;
    const char* Bs = As + BM * 128;
#pragma unroll
    for (int kk = 0; kk < 2; ++kk) {
      f16x8 afr[WM], bfr[WN];
#pragma unroll
      for (int n = 0; n < WN; ++n) bfr[n] = ldfrag(Bs, wc + n * 16 + lr, kk, lq);
#pragma unroll
      for (int m = 0; m < WM; ++m) afr[m] = ldfrag(As, wr + m * 16 + lr, kk, lq);
      __builtin_amdgcn_s_setprio(1);
#pragma unroll
      for (int m = 0; m < WM; ++m)
#pragma unroll
        for (int n = 0; n < WN; ++n)
          acc[m][n] = __builtin_amdgcn_mfma_f32_16x16x32_f16(afr[m], bfr[n],
                                                             acc[m][n], 0, 0, 0);
      __builtin_amdgcn_s_setprio(0);
    }
    if (NBUF == 2) __builtin_amdgcn_s_barrier();  // fence buf rewrite next iter
  }

  // Epilogue. C/D layout (m89-verified): col = lane&15, row = (lane>>4)*4 + j.
  if (MODE == 0) {
#pragma unroll
    for (int m = 0; m < WM; ++m)
#pragma unroll
      for (int n = 0; n < WN; ++n) {
        const int gcol = n0 + wc + n * 16 + lr;
        const float bv = bias[gcol];
#pragma unroll
        for (int j = 0; j < 4; ++j) {
          const int grow = m0 + wr + m * 16 + lq * 4 + j;
          const float t = fast_tanh(acc[m][n][j] + bv);
          if (gcol < HID)
            Hout[(size_t)grow * HID + gcol] = (_Float16)t;
          else
            kmem[(size_t)grow * DIM + (gcol - HID)] = (_Float16)t;
        }
      }
  } else {
    const float h = tg[step + 1] - tg[step];
#pragma unroll
    for (int m = 0; m < WM; ++m)
#pragma unroll
      for (int n = 0; n < WN; ++n) {
        const int gcol = n0 + wc + n * 16 + lr;
        const float bv = b2[gcol];
#pragma unroll
        for (int j = 0; j < 4; ++j) {
          const int grow = m0 + wr + m * 16 + lq * 4 + j;
          const size_t idx = (size_t)grow * DIM + gcol;
          const float kv = acc[m][n][j] + (float)kmem[idx] + bv;
          if (MODE == 1) {
            const float av = initf ? kv : ((float)accb[idx] + 2.0f * kv);
            accb[idx] = (_Float16)av;
            const float tv = y[idx] + (hmul * h) * kv;
            ts[idx] = (_Float16)tv;
          } else {
            const float v =
                y[idx] + (h * (1.0f / 6.0f)) * ((float)accb[idx] + kv);
            y[idx] = v;
            out_row[idx] = v;
            ts[idx] = (_Float16)v;
          }
        }
      }
  }
}

// ---------- merged one-time prep: weights + bias + state init ----------
__global__ __launch_bounds__(256) void prep_k(
    const float* __restrict__ x, const float* __restrict__ W1,
    const float* __restrict__ b1, const float* __restrict__ W2,
    const float* __restrict__ Wm, const float* __restrict__ bmv,
    float* __restrict__ y, float* __restrict__ out0,
    _Float16* __restrict__ ys, _Float16* __restrict__ WcatT,
    _Float16* __restrict__ W2T, float* __restrict__ bias_cat) {
  const int idx = blockIdx.x * 256 + threadIdx.x;

  // Job 1: WcatT [NCAT][DIM] = concat(W1^T, Wm^T)   (NCAT*DIM threads)
  {
    const int nrow = idx / DIM, k = idx % DIM;
    const float v = (nrow < HID) ? W1[(size_t)k * HID + nrow]
                                 : Wm[(size_t)k * DIM + (nrow - HID)];
    WcatT[idx] = (_Float16)v;
  }
  // Job 2: W2T [DIM][HID] = W2^T   (DIM*HID threads)
  if (idx < DIM * HID) {
    const int nrow = idx / HID, k = idx % HID;
    W2T[idx] = (_Float16)W2[(size_t)k * DIM + nrow];
  }
  // Job 3: bias_cat [NCAT]
  if (idx < NCAT) bias_cat[idx] = (idx < HID) ? b1[idx] : bmv[idx - HID];
  // Job 4: state init (NELEM/4 threads, float4 lanes)
  if (idx < NELEM / 4) {
    const int base = idx * 4;
    f32x4 v = *(const f32x4*)(x + base);
    *(f32x4*)(y + base) = v;
    *(f32x4*)(out0 + base) = v;
    f16x4 hv;
#pragma unroll
    for (int j = 0; j < 4; ++j) hv[j] = (_Float16)v[j];
    *(f16x4*)(ys + base) = hv;
  }
}

extern "C" void kernel_launch(void* const* d_in, const int* in_sizes, int n_in,
                              void* d_out, int out_size, void* d_ws,
                              size_t ws_size, hipStream_t stream) {
  const float* x  = (const float*)d_in[0];
  const float* tg = (const float*)d_in[1];
  const float* W1 = (const float*)d_in[2];
  const float* b1 = (const float*)d_in[3];
  const float* W2 = (const float*)d_in[4];
  const float* b2 = (const float*)d_in[5];
  const float* Wm = (const float*)d_in[6];
  const float* bm = (const float*)d_in[7];
  float* out = (float*)d_out;
  const int T = in_sizes[1];  // 32

  // ---- workspace partition (~30 MB) ----
  float* y        = (float*)d_ws;               // NELEM f32
  float* bias_cat = y + NELEM;                  // NCAT
  _Float16* kmem  = (_Float16*)(bias_cat + NCAT);  // NELEM fp16
  _Float16* accb  = kmem + NELEM;                  // NELEM fp16
  _Float16* ys    = accb + NELEM;                  // NELEM (state y, fp16)
  _Float16* ts    = ys + NELEM;                    // NELEM (stage state)
  _Float16* Hh    = ts + NELEM;                    // BATCH*HID
  _Float16* WcatT = Hh + (size_t)BATCH * HID;      // NCAT*DIM
  _Float16* W2T   = WcatT + (size_t)NCAT * DIM;    // DIM*HID

  // ---- one-time prep (single launch: weights, bias, state init) ----
  prep_k<<<(NCAT * DIM) / 256, 256, 0, stream>>>(x, W1, b1, W2, Wm, bm, y, out,
                                                 ys, WcatT, W2T, bias_cat);

  auto gemm0 = [&](const _Float16* a) {
    gemm_k<0, 64, 96, 12><<<768, 256, 0, stream>>>(
        a, WcatT, bias_cat, Hh, kmem, nullptr, nullptr, nullptr, nullptr,
        nullptr, nullptr, 0, 0.f, 0);
  };
  auto gemm1_stage = [&](int step, float hmul, int initf) {
    gemm_k<1, 32, 96, 24><<<512, 256, 0, stream>>>(
        Hh, W2T, nullptr, nullptr, kmem, b2, y, accb, ts, nullptr, tg, step,
        hmul, initf);
  };
  auto gemm1_final = [&](int step, float* orow) {
    gemm_k<2, 32, 96, 24><<<512, 256, 0, stream>>>(
        Hh, W2T, nullptr, nullptr, kmem, b2, y, accb, ys, orow, tg, step, 0.f,
        0);
  };

  for (int i = 0; i < T - 1; ++i) {
    gemm0(ys);  gemm1_stage(i, 0.5f, 1);   // k1
    gemm0(ts);  gemm1_stage(i, 0.5f, 0);   // k2
    gemm0(ts);  gemm1_stage(i, 1.0f, 0);   // k3
    gemm0(ts);  gemm1_final(i, out + (size_t)(i + 1) * NELEM);  // k4
  }
}